// Round 3
// baseline (1489.241 us; speedup 1.0000x reference)
//
#include <hip/hip_runtime.h>

// iResBlock logdet estimator — fused, 32x32x16 bf16 MFMA, 3-term hi/lo split.
// B=131072 rows, D=64, H=256, 10 power-series VJP iterations.
// 32 rows/wave, 4 waves/block, 1024 blocks, no __syncthreads anywhere.
// s = elu'(z) held as u16 fixed-point (scale folded into W1u pre-split).
// Weight fragments packed hi|lo interleaved (32B per lane-pair) for L1/L2.

typedef __attribute__((ext_vector_type(4))) float f32x4;
typedef __attribute__((ext_vector_type(16))) float f32x16;
typedef __attribute__((ext_vector_type(8))) short short8;

#define MFMA32(a, b, c) __builtin_amdgcn_mfma_f32_32x32x16_bf16(a, b, c, 0, 0, 0)

// Packed pre-split weights: fragment granularity 8 shorts; hi frag at
// pk[2*off .. +7], lo frag at pk[2*off+8 .. +15]  (off = 8-aligned elem idx).
// w1t [h][kcat=128]: B for z = [x|u]@W1cat (contig in kcat)
// w2t [d][h]       : B for g = h@W2        (contig in h)
// w2  [h][d] orig  : B for t = w@W2^T      (contig in d)
// w1u [d][h] orig  : B for wn = ts@W1u^T   (contig in h), pre-scaled 1/65535
__device__ __align__(16) short g_w1t_pk[65536];
__device__ __align__(16) short g_w2t_pk[32768];
__device__ __align__(16) short g_w2_pk[32768];
__device__ __align__(16) short g_w1u_pk[32768];

__device__ inline unsigned short bf16r(float f) {  // RNE bf16
  unsigned uu = __float_as_uint(f);
  return (unsigned short)((uu + 0x7FFFu + ((uu >> 16) & 1u)) >> 16);
}

__device__ inline void splitf(float f, short& h, short& l) {
  unsigned uu = __float_as_uint(f);
  unsigned r = uu + 0x7FFFu + ((uu >> 16) & 1u);
  h = (short)(r >> 16);
  float fh = __uint_as_float(r & 0xFFFF0000u);
  l = (short)bf16r(f - fh);
}

__device__ inline void split8(f32x4 a, f32x4 b, short8& hi, short8& lo) {
#pragma unroll
  for (int i = 0; i < 4; i++) {
    short hh, ll;
    splitf(a[i], hh, ll);
    hi[i] = hh;
    lo[i] = ll;
  }
#pragma unroll
  for (int i = 0; i < 4; i++) {
    short hh, ll;
    splitf(b[i], hh, ll);
    hi[4 + i] = hh;
    lo[4 + i] = ll;
  }
}

__device__ inline void store_pk(short* arr, int i, float v) {
  short h, l;
  splitf(v, h, l);
  const int d = 2 * (i & ~7) + (i & 7);
  arr[d] = h;
  arr[d + 8] = l;
}

__global__ void prep_weights(const float* __restrict__ W1x,
                             const float* __restrict__ W1u,
                             const float* __restrict__ W2) {
  const int tid = blockIdx.x * blockDim.x + threadIdx.x;
  const int nth = gridDim.x * blockDim.x;
  const float inv = 1.f / 65535.f;
  for (int i = tid; i < 32768; i += nth) {
    int h = i >> 7, k = i & 127;
    store_pk(g_w1t_pk, i, (k < 64) ? W1x[k * 256 + h] : W1u[(k - 64) * 256 + h]);
  }
  for (int i = tid; i < 16384; i += nth) {
    int d = i >> 8, h = i & 255;
    store_pk(g_w2t_pk, i, W2[h * 64 + d]);
  }
  for (int i = tid; i < 16384; i += nth) store_pk(g_w2_pk, i, W2[i]);
  for (int i = tid; i < 16384; i += nth) store_pk(g_w1u_pk, i, W1u[i] * inv);
}

// XOR-swizzled word index for the per-wave [32 rows][32 cols] f32 exchange
// buffer. Writes (fixed reg, col=lane): 2 banks-hits/bank (free, m136).
// b128 reads (row=lane&31, 4 consecutive cols): uniform 8 words/bank floor.
__device__ inline int swz(int row, int col) {
  return row * 32 + (col ^ ((row & 7) << 2));
}

__device__ inline int drow(int r, int hb) {  // 32x32 D-layout row (m74/m101)
  return (r & 3) + 8 * (r >> 2) + 4 * hb;
}

// Exchange a D-layout f32x16 tile into two k16 A-fragments (hi/lo split).
__device__ inline void exch2(float* buf, const f32x16& t, int hb, int c32,
                             short8& ah0, short8& al0, short8& ah1,
                             short8& al1) {
#pragma unroll
  for (int r = 0; r < 16; r++) buf[swz(drow(r, hb), c32)] = t[r];
  f32x4 fa = *(const f32x4*)&buf[swz(c32, hb * 8)];
  f32x4 fb = *(const f32x4*)&buf[swz(c32, hb * 8 + 4)];
  split8(fa, fb, ah0, al0);
  fa = *(const f32x4*)&buf[swz(c32, 16 + hb * 8)];
  fb = *(const f32x4*)&buf[swz(c32, 16 + hb * 8 + 4)];
  split8(fa, fb, ah1, al1);
}

__global__ __launch_bounds__(256, 2) void iresblock_fused(
    const float* __restrict__ x, const float* __restrict__ u,
    const float* __restrict__ logpx, const float* __restrict__ eps,
    const float* __restrict__ b1, const float* __restrict__ b2,
    float* __restrict__ out) {
  constexpr int BD = 131072 * 64;
  __shared__ __align__(16) float lds[4][2][1024];  // 2 exchange bufs / wave
  const int lane = threadIdx.x & 63;
  const int wave = threadIdx.x >> 6;
  const int c32 = lane & 31, hb = lane >> 5;
  const int row0 = (blockIdx.x * 4 + wave) * 32;  // this wave's 32 rows
  const f32x16 z16 = {0.f, 0.f, 0.f, 0.f, 0.f, 0.f, 0.f, 0.f,
                      0.f, 0.f, 0.f, 0.f, 0.f, 0.f, 0.f, 0.f};

  // ---- output 0: copy x through (8 KB contiguous per wave, NT stores)
  {
    const float* src = x + row0 * 64;
    float* dst = out + row0 * 64;
#pragma unroll
    for (int i = 0; i < 8; i++) {
      f32x4 v = *(const f32x4*)(src + i * 256 + lane * 4);
      __builtin_nontemporal_store(v, (f32x4*)(dst + i * 256 + lane * 4));
    }
  }

  // ---- A-fragments for matmul1 from global x|u.
  // A[row=c32][k = ks*16 + hb*8 + i]; k<64 -> x, else u. (A and B use the
  // same k-slot mapping, so the HW-internal k permutation cancels.)
  short8 a1h[8], a1l[8];
  {
    const int arow = row0 + c32;
#pragma unroll
    for (int ks = 0; ks < 8; ks++) {
      const float* p = (ks < 4 ? x : u) + arow * 64 + (ks & 3) * 16 + hb * 8;
      split8(*(const f32x4*)p, *(const f32x4*)(p + 4), a1h[ks], a1l[ks]);
    }
  }

  // ---- phase 1: per 32-col h-tile: z -> h=elu(z) -> {pack s, feed matmul2}
  unsigned spk[8][8];  // s = elu'(z) as u16 fixed (r even|odd), [nt][r>>1]
  f32x16 gacc[2] = {z16, z16};
#pragma unroll
  for (int nt = 0; nt < 8; nt++) {
    f32x16 zacc = z16;
#pragma unroll
    for (int ks = 0; ks < 8; ks++) {
      const short* p = g_w1t_pk + 2 * ((nt * 32 + c32) * 128 + ks * 16 + hb * 8);
      short8 bh = *(const short8*)p;
      short8 bl = *(const short8*)(p + 8);
      zacc = MFMA32(a1h[ks], bh, zacc);
      zacc = MFMA32(a1h[ks], bl, zacc);
      zacc = MFMA32(a1l[ks], bh, zacc);
    }
    const float bias = b1[nt * 32 + c32];
    f32x16 hv;
#pragma unroll
    for (int r = 0; r < 16; r++) {
      float z = zacc[r] + bias;
      hv[r] = z > 0.f ? z : __expf(z) - 1.f;  // elu (abs err ~1e-7, safe)
    }
#pragma unroll
    for (int rp = 0; rp < 8; rp++) {  // s = 1 (z>0) else e^z = h+1, in (0,1]
      float s0 = hv[2 * rp] > 0.f ? 1.f : hv[2 * rp] + 1.f;
      float s1 = hv[2 * rp + 1] > 0.f ? 1.f : hv[2 * rp + 1] + 1.f;
      spk[nt][rp] = ((unsigned)(s1 * 65535.f + 0.5f) << 16) |
                    (unsigned)(s0 * 65535.f + 0.5f);
    }
    // matmul2 contribution: this tile is k-chunk nt of g = h@W2
    short8 a2h[2], a2l[2];
    exch2(&lds[wave][nt & 1][0], hv, hb, c32, a2h[0], a2l[0], a2h[1], a2l[1]);
#pragma unroll
    for (int dt = 0; dt < 2; dt++)
#pragma unroll
      for (int kk = 0; kk < 2; kk++) {
        const short* p =
            g_w2t_pk + 2 * ((dt * 32 + c32) * 256 + nt * 32 + kk * 16 + hb * 8);
        short8 bh = *(const short8*)p;
        short8 bl = *(const short8*)(p + 8);
        gacc[dt] = MFMA32(a2h[kk], bh, gacc[dt]);
        gacc[dt] = MFMA32(a2h[kk], bl, gacc[dt]);
        gacc[dt] = MFMA32(a2l[kk], bh, gacc[dt]);
      }
  }

  // ---- output 1: v = u + g + b2 (NT stores)
#pragma unroll
  for (int dt = 0; dt < 2; dt++) {
    const float bias = b2[dt * 32 + c32];
#pragma unroll
    for (int r = 0; r < 16; r++) {
      const int rw = row0 + drow(r, hb);
      const int d = dt * 32 + c32;
      __builtin_nontemporal_store(u[rw * 64 + d] + gacc[dt][r] + bias,
                                  &out[BD + rw * 64 + d]);
    }
  }

  // ---- eps in D-layout; w0 = eps -> initial A-fragments
  f32x16 e0, e1;
#pragma unroll
  for (int r = 0; r < 16; r++) {
    e0[r] = eps[(row0 + drow(r, hb)) * 64 + c32];
    e1[r] = eps[(row0 + drow(r, hb)) * 64 + 32 + c32];
  }
  short8 a3h[4], a3l[4];
  exch2(&lds[wave][0][0], e0, hb, c32, a3h[0], a3l[0], a3h[1], a3l[1]);
  exch2(&lds[wave][1][0], e1, hb, c32, a3h[2], a3l[2], a3h[3], a3l[3]);

  float ld[16];
#pragma unroll
  for (int r = 0; r < 16; r++) ld[r] = 0.f;

  // ---- power series: wn = ((w @ W2^T) * s) @ W1u^T, 10 iterations
#pragma unroll 1
  for (int k = 1; k <= 10; k++) {
    f32x16 wn[2] = {z16, z16};
#pragma unroll
    for (int nt = 0; nt < 8; nt++) {
      // t-tile (32 h-cols): t = w @ W2^T
      f32x16 tacc = z16;
      __builtin_amdgcn_s_setprio(1);
#pragma unroll
      for (int ks = 0; ks < 4; ks++) {
        const short* p =
            g_w2_pk + 2 * ((nt * 32 + c32) * 64 + ks * 16 + hb * 8);
        short8 bh = *(const short8*)p;
        short8 bl = *(const short8*)(p + 8);
        tacc = MFMA32(a3h[ks], bh, tacc);
        tacc = MFMA32(a3h[ks], bl, tacc);
        tacc = MFMA32(a3l[ks], bh, tacc);
      }
      __builtin_amdgcn_s_setprio(0);
      // ts = t * s   (D-layout matches s's stored layout; u16 fixed-point,
      // 1/65535 pre-folded into g_w1u_pk)
#pragma unroll
      for (int r = 0; r < 16; r++) {
        float sv = (float)((spk[nt][r >> 1] >> ((r & 1) * 16)) & 0xFFFFu);
        tacc[r] *= sv;
      }
      // k-chunk nt of wn = ts @ W1u^T
      short8 a4h[2], a4l[2];
      exch2(&lds[wave][nt & 1][0], tacc, hb, c32, a4h[0], a4l[0], a4h[1],
            a4l[1]);
      __builtin_amdgcn_s_setprio(1);
#pragma unroll
      for (int dt = 0; dt < 2; dt++)
#pragma unroll
        for (int kk = 0; kk < 2; kk++) {
          const short* p = g_w1u_pk +
                           2 * ((dt * 32 + c32) * 256 + nt * 32 + kk * 16 + hb * 8);
          short8 bh = *(const short8*)p;
          short8 bl = *(const short8*)(p + 8);
          wn[dt] = MFMA32(a4h[kk], bh, wn[dt]);
          wn[dt] = MFMA32(a4h[kk], bl, wn[dt]);
          wn[dt] = MFMA32(a4l[kk], bh, wn[dt]);
        }
      __builtin_amdgcn_s_setprio(0);
    }
    // per-lane logdet partials (cross-lane reduce deferred to the end)
    const float coeff = ((k & 1) ? 1.f : -1.f) / (float)k;
#pragma unroll
    for (int r = 0; r < 16; r++)
      ld[r] += coeff * (wn[0][r] * e0[r] + wn[1][r] * e1[r]);
    // wn -> next iteration's A-fragments (skip on the final iteration)
    if (k < 10) {
      exch2(&lds[wave][0][0], wn[0], hb, c32, a3h[0], a3l[0], a3h[1], a3l[1]);
      exch2(&lds[wave][1][0], wn[1], hb, c32, a3h[2], a3l[2], a3h[3], a3l[3]);
    }
  }

  // ---- reduce over the 32 lanes sharing each row (hb half preserved)
#pragma unroll
  for (int r = 0; r < 16; r++)
#pragma unroll
    for (int m = 1; m < 32; m <<= 1) ld[r] += __shfl_xor(ld[r], m, 64);

  // ---- output 2: logpx - logdet
#pragma unroll
  for (int r = 0; r < 16; r++)
    if (c32 == r) {
      const int rw = row0 + drow(r, hb);
      out[2 * BD + rw] = logpx[rw] - ld[r];
    }
}

extern "C" void kernel_launch(void* const* d_in, const int* in_sizes, int n_in,
                              void* d_out, int out_size, void* d_ws,
                              size_t ws_size, hipStream_t stream) {
  (void)in_sizes;
  (void)n_in;
  (void)out_size;
  (void)d_ws;
  (void)ws_size;
  const float* x = (const float*)d_in[0];
  const float* u = (const float*)d_in[1];
  const float* logpx = (const float*)d_in[2];
  const float* eps = (const float*)d_in[3];
  const float* W1x = (const float*)d_in[4];
  const float* W1u = (const float*)d_in[5];
  const float* b1 = (const float*)d_in[6];
  const float* W2 = (const float*)d_in[7];
  const float* b2 = (const float*)d_in[8];
  float* out = (float*)d_out;

  prep_weights<<<32, 256, 0, stream>>>(W1x, W1u, W2);
  iresblock_fused<<<1024, 256, 0, stream>>>(x, u, logpx, eps, b1, b2, out);
}

// Round 4
// 1198.661 us; speedup vs baseline: 1.2424x; 1.2424x over previous
//
#include <hip/hip_runtime.h>

// iResBlock logdet estimator — fused, 32x32x16 bf16 MFMA, 3-term hi/lo split.
// B=131072 rows, D=64, H=256, 10 power-series VJP iterations.
// 512-thread blocks (8 waves x 32 rows), 512 blocks.
// Power-loop weights (W2^T, W1u^T hi/lo = 128KB) staged in LDS, XOR-swizzled.
// Phase-1 weights in global with fragment-major (coalesced) layout.

typedef __attribute__((ext_vector_type(4))) float f32x4;
typedef __attribute__((ext_vector_type(16))) float f32x16;
typedef __attribute__((ext_vector_type(8))) short short8;

#define MFMA32(a, b, c) __builtin_amdgcn_mfma_f32_32x32x16_bf16(a, b, c, 0, 0, 0)

// Global pre-split weights.
// g_w1t_pk: frag-major. Unit U = nt*512 + ks*64 + c32*2 + hb holds 8 hi
//   shorts then 8 lo shorts for B[col=nt*32+c32][k=ks*16+hb*8 ..+8) of
//   W1cat^T [h][kcat=128]. A wave's (nt,ks) load = contiguous 2KB.
// g_w2t_pk: frag-major for W2^T-as-[d][h]: U = (nt*2+kk)*128 + d*2 + hb.
// g_w2_pk / g_w1u_pk: elem-group layout (8-elem groups, hi8|lo8 = 32B),
//   copied into LDS; w1u pre-scaled by 1/65535 (s fixed-point fold).
__device__ __align__(16) short g_w1t_pk[65536];
__device__ __align__(16) short g_w2t_pk[32768];
__device__ __align__(16) short g_w2_pk[32768];
__device__ __align__(16) short g_w1u_pk[32768];

__device__ inline unsigned short bf16r(float f) {  // RNE bf16
  unsigned uu = __float_as_uint(f);
  return (unsigned short)((uu + 0x7FFFu + ((uu >> 16) & 1u)) >> 16);
}

__device__ inline void splitf(float f, short& h, short& l) {
  unsigned uu = __float_as_uint(f);
  unsigned r = uu + 0x7FFFu + ((uu >> 16) & 1u);
  h = (short)(r >> 16);
  float fh = __uint_as_float(r & 0xFFFF0000u);
  l = (short)bf16r(f - fh);
}

__device__ inline void split8(f32x4 a, f32x4 b, short8& hi, short8& lo) {
#pragma unroll
  for (int i = 0; i < 4; i++) {
    short hh, ll;
    splitf(a[i], hh, ll);
    hi[i] = hh;
    lo[i] = ll;
  }
#pragma unroll
  for (int i = 0; i < 4; i++) {
    short hh, ll;
    splitf(b[i], hh, ll);
    hi[4 + i] = hh;
    lo[4 + i] = ll;
  }
}

__device__ inline void store_pk(short* arr, int i, float v) {  // elem-group
  short h, l;
  splitf(v, h, l);
  const int d = 2 * (i & ~7) + (i & 7);
  arr[d] = h;
  arr[d + 8] = l;
}

__global__ void prep_weights(const float* __restrict__ W1x,
                             const float* __restrict__ W1u,
                             const float* __restrict__ W2) {
  const int tid = blockIdx.x * blockDim.x + threadIdx.x;
  const int nth = gridDim.x * blockDim.x;
  const float inv = 1.f / 65535.f;
  for (int i = tid; i < 32768; i += nth) {  // w1t, frag-major
    int col = i >> 7, k = i & 127;
    float v = (k < 64) ? W1x[k * 256 + col] : W1u[(k - 64) * 256 + col];
    short hh, ll;
    splitf(v, hh, ll);
    int U = (col >> 5) * 512 + (k >> 4) * 64 + (col & 31) * 2 + ((k >> 3) & 1);
    int j = k & 7;
    g_w1t_pk[U * 16 + j] = hh;
    g_w1t_pk[U * 16 + 8 + j] = ll;
  }
  for (int i = tid; i < 16384; i += nth) {  // w2t, frag-major
    int d = i >> 8, h = i & 255;
    short hh, ll;
    splitf(W2[h * 64 + d], hh, ll);
    int U = (h >> 4) * 128 + d * 2 + ((h >> 3) & 1);
    int j = h & 7;
    g_w2t_pk[U * 16 + j] = hh;
    g_w2t_pk[U * 16 + 8 + j] = ll;
  }
  for (int i = tid; i < 16384; i += nth) store_pk(g_w2_pk, i, W2[i]);
  for (int i = tid; i < 16384; i += nth) store_pk(g_w1u_pk, i, W1u[i] * inv);
}

// Exchange-buffer swizzle ([32 rows][32 cols] f32 per wave): writes 2/bank
// (free), b128 reads at the 8-words/bank floor.
__device__ inline int swz(int row, int col) {
  return row * 32 + (col ^ ((row & 7) << 2));
}

__device__ inline int drow(int r, int hb) {  // 32x32 D-layout row (m74/m101)
  return (r & 3) + 8 * (r >> 2) + 4 * hb;
}

// Exchange a D-layout f32x16 tile into two k16 A-fragments (hi/lo split).
__device__ inline void exch2(float* buf, const f32x16& t, int hb, int c32,
                             short8& ah0, short8& al0, short8& ah1,
                             short8& al1) {
#pragma unroll
  for (int r = 0; r < 16; r++) buf[swz(drow(r, hb), c32)] = t[r];
  f32x4 fa = *(const f32x4*)&buf[swz(c32, hb * 8)];
  f32x4 fb = *(const f32x4*)&buf[swz(c32, hb * 8 + 4)];
  split8(fa, fb, ah0, al0);
  fa = *(const f32x4*)&buf[swz(c32, 16 + hb * 8)];
  fb = *(const f32x4*)&buf[swz(c32, 16 + hb * 8 + 4)];
  split8(fa, fb, ah1, al1);
}

__global__ __launch_bounds__(512, 2) void iresblock_fused(
    const float* __restrict__ x, const float* __restrict__ u,
    const float* __restrict__ logpx, const float* __restrict__ eps,
    const float* __restrict__ b1, const float* __restrict__ b2,
    float* __restrict__ out) {
  constexpr int BD = 131072 * 64;
  // 64KB + 64KB staged weights + 8 x 4KB exchange = 160KB (full CU pool).
  __shared__ __align__(16) short s_w2[32768];
  __shared__ __align__(16) short s_w1u[32768];
  __shared__ __align__(16) float s_xch[8][1024];
  const int lane = threadIdx.x & 63;
  const int wave = threadIdx.x >> 6;
  const int c32 = lane & 31, hb = lane >> 5;
  const int k7 = c32 & 7;
  float* buf = &s_xch[wave][0];
  const int row0 = (blockIdx.x * 8 + wave) * 32;  // this wave's 32 rows
  const f32x16 z16 = {0.f, 0.f, 0.f, 0.f, 0.f, 0.f, 0.f, 0.f,
                      0.f, 0.f, 0.f, 0.f, 0.f, 0.f, 0.f, 0.f};

  // ---- cooperative LDS stage of power-loop weights (XOR-swizzled slots).
  // Slot s (16B) layout: w2: bits0-3 = {is_lo,hb,ks}, bits4+ = col (h).
  //                      w1u: bits0-5 = {is_lo,hb,kk,nt}, bits6+ = col (d).
  for (int s = threadIdx.x; s < 4096; s += 512) {
    *(f32x4*)&s_w2[(s ^ ((s >> 4) & 7)) * 8] = *(const f32x4*)&g_w2_pk[s * 8];
    *(f32x4*)&s_w1u[(s ^ ((s >> 6) & 7)) * 8] =
        *(const f32x4*)&g_w1u_pk[s * 8];
  }
  __syncthreads();  // only barrier in the kernel

  // ---- output 0: copy x through (8 KB contiguous per wave, NT stores)
  {
    const float* src = x + row0 * 64;
    float* dst = out + row0 * 64;
#pragma unroll
    for (int i = 0; i < 8; i++) {
      f32x4 v = *(const f32x4*)(src + i * 256 + lane * 4);
      __builtin_nontemporal_store(v, (f32x4*)(dst + i * 256 + lane * 4));
    }
  }

  // ---- A-fragments for matmul1 from global x|u.
  short8 a1h[8], a1l[8];
  {
    const int arow = row0 + c32;
#pragma unroll
    for (int ks = 0; ks < 8; ks++) {
      const float* p = (ks < 4 ? x : u) + arow * 64 + (ks & 3) * 16 + hb * 8;
      split8(*(const f32x4*)p, *(const f32x4*)(p + 4), a1h[ks], a1l[ks]);
    }
  }

  // ---- phase 1: per 32-col h-tile: z -> h=elu(z) -> {pack s, feed matmul2}
  unsigned spk[8][8];  // s = elu'(z) as u16 fixed pairs, [nt][r>>1]
  f32x16 gacc[2] = {z16, z16};
#pragma unroll
  for (int nt = 0; nt < 8; nt++) {
    f32x16 za = z16, zb = z16;  // split accumulator chains for MFMA ILP
#pragma unroll
    for (int ks = 0; ks < 4; ks++) {
      const short* p = g_w1t_pk + (nt * 512 + ks * 64 + c32 * 2 + hb) * 16;
      short8 bh = *(const short8*)p;
      short8 bl = *(const short8*)(p + 8);
      za = MFMA32(a1h[ks], bh, za);
      za = MFMA32(a1h[ks], bl, za);
      za = MFMA32(a1l[ks], bh, za);
    }
#pragma unroll
    for (int ks = 4; ks < 8; ks++) {
      const short* p = g_w1t_pk + (nt * 512 + ks * 64 + c32 * 2 + hb) * 16;
      short8 bh = *(const short8*)p;
      short8 bl = *(const short8*)(p + 8);
      zb = MFMA32(a1h[ks], bh, zb);
      zb = MFMA32(a1h[ks], bl, zb);
      zb = MFMA32(a1l[ks], bh, zb);
    }
    f32x16 zacc = za + zb;
    const float bias = b1[nt * 32 + c32];
    f32x16 hv;
#pragma unroll
    for (int r = 0; r < 16; r++) {
      float z = zacc[r] + bias;
      hv[r] = z > 0.f ? z : __expf(z) - 1.f;  // elu
    }
#pragma unroll
    for (int rp = 0; rp < 8; rp++) {  // s = 1 (z>0) else e^z = h+1, in (0,1]
      float s0 = hv[2 * rp] > 0.f ? 1.f : hv[2 * rp] + 1.f;
      float s1 = hv[2 * rp + 1] > 0.f ? 1.f : hv[2 * rp + 1] + 1.f;
      spk[nt][rp] = ((unsigned)(s1 * 65535.f + 0.5f) << 16) |
                    (unsigned)(s0 * 65535.f + 0.5f);
    }
    // matmul2 contribution: this tile is k-chunk nt of g = h@W2
    short8 a2h[2], a2l[2];
    exch2(buf, hv, hb, c32, a2h[0], a2l[0], a2h[1], a2l[1]);
#pragma unroll
    for (int dt = 0; dt < 2; dt++)
#pragma unroll
      for (int kk = 0; kk < 2; kk++) {
        const short* p =
            g_w2t_pk + ((nt * 2 + kk) * 128 + dt * 64 + c32 * 2 + hb) * 16;
        short8 bh = *(const short8*)p;
        short8 bl = *(const short8*)(p + 8);
        gacc[dt] = MFMA32(a2h[kk], bh, gacc[dt]);
        gacc[dt] = MFMA32(a2h[kk], bl, gacc[dt]);
        gacc[dt] = MFMA32(a2l[kk], bh, gacc[dt]);
      }
  }

  // ---- output 1: v = u + g + b2 (NT stores)
#pragma unroll
  for (int dt = 0; dt < 2; dt++) {
    const float bias = b2[dt * 32 + c32];
#pragma unroll
    for (int r = 0; r < 16; r++) {
      const int rw = row0 + drow(r, hb);
      const int d = dt * 32 + c32;
      __builtin_nontemporal_store(u[rw * 64 + d] + gacc[dt][r] + bias,
                                  &out[BD + rw * 64 + d]);
    }
  }

  // ---- eps in D-layout; w0 = eps -> initial A-fragments
  f32x16 e0, e1;
#pragma unroll
  for (int r = 0; r < 16; r++) {
    e0[r] = eps[(row0 + drow(r, hb)) * 64 + c32];
    e1[r] = eps[(row0 + drow(r, hb)) * 64 + 32 + c32];
  }
  short8 a3h[4], a3l[4];
  exch2(buf, e0, hb, c32, a3h[0], a3l[0], a3h[1], a3l[1]);
  exch2(buf, e1, hb, c32, a3h[2], a3l[2], a3h[3], a3l[3]);

  float ld[16];
#pragma unroll
  for (int r = 0; r < 16; r++) ld[r] = 0.f;

  // ---- power series: wn = ((w @ W2^T) * s) @ W1u^T, 10 iterations.
  // All B-frags from swizzled LDS.
#pragma unroll 1
  for (int k = 1; k <= 10; k++) {
    f32x16 wn[2] = {z16, z16};
#pragma unroll
    for (int nt = 0; nt < 8; nt++) {
      // t-tile (32 h-cols): t = w @ W2^T   (B from s_w2)
      f32x16 ta = z16, tb = z16;
      __builtin_amdgcn_s_setprio(1);
#pragma unroll
      for (int ks = 0; ks < 2; ks++) {
        const int slot = nt * 512 + c32 * 16 + ks * 4 + hb * 2;
        short8 bh = *(const short8*)&s_w2[(slot ^ k7) * 8];
        short8 bl = *(const short8*)&s_w2[((slot + 1) ^ k7) * 8];
        ta = MFMA32(a3h[ks], bh, ta);
        ta = MFMA32(a3h[ks], bl, ta);
        ta = MFMA32(a3l[ks], bh, ta);
      }
#pragma unroll
      for (int ks = 2; ks < 4; ks++) {
        const int slot = nt * 512 + c32 * 16 + ks * 4 + hb * 2;
        short8 bh = *(const short8*)&s_w2[(slot ^ k7) * 8];
        short8 bl = *(const short8*)&s_w2[((slot + 1) ^ k7) * 8];
        tb = MFMA32(a3h[ks], bh, tb);
        tb = MFMA32(a3h[ks], bl, tb);
        tb = MFMA32(a3l[ks], bh, tb);
      }
      __builtin_amdgcn_s_setprio(0);
      f32x16 tacc = ta + tb;
      // ts = t * s   (u16 fixed-point; 1/65535 pre-folded into w1u)
#pragma unroll
      for (int r = 0; r < 16; r++) {
        float sv = (float)((spk[nt][r >> 1] >> ((r & 1) * 16)) & 0xFFFFu);
        tacc[r] *= sv;
      }
      // k-chunk nt of wn = ts @ W1u^T   (B from s_w1u)
      short8 a4h[2], a4l[2];
      exch2(buf, tacc, hb, c32, a4h[0], a4l[0], a4h[1], a4l[1]);
      __builtin_amdgcn_s_setprio(1);
#pragma unroll
      for (int dt = 0; dt < 2; dt++)
#pragma unroll
        for (int kk = 0; kk < 2; kk++) {
          const int slot =
              (dt * 32 + c32) * 64 + nt * 8 + kk * 4 + hb * 2;
          short8 bh = *(const short8*)&s_w1u[(slot ^ k7) * 8];
          short8 bl = *(const short8*)&s_w1u[((slot + 1) ^ k7) * 8];
          wn[dt] = MFMA32(a4h[kk], bh, wn[dt]);
          wn[dt] = MFMA32(a4h[kk], bl, wn[dt]);
          wn[dt] = MFMA32(a4l[kk], bh, wn[dt]);
        }
      __builtin_amdgcn_s_setprio(0);
    }
    // per-lane logdet partials (cross-lane reduce deferred to the end)
    const float coeff = ((k & 1) ? 1.f : -1.f) / (float)k;
#pragma unroll
    for (int r = 0; r < 16; r++)
      ld[r] += coeff * (wn[0][r] * e0[r] + wn[1][r] * e1[r]);
    // wn -> next iteration's A-fragments (skip on final iteration)
    if (k < 10) {
      exch2(buf, wn[0], hb, c32, a3h[0], a3l[0], a3h[1], a3l[1]);
      exch2(buf, wn[1], hb, c32, a3h[2], a3l[2], a3h[3], a3l[3]);
    }
  }

  // ---- reduce over the 32 lanes sharing each row (hb half preserved)
#pragma unroll
  for (int r = 0; r < 16; r++)
#pragma unroll
    for (int m = 1; m < 32; m <<= 1) ld[r] += __shfl_xor(ld[r], m, 64);

  // ---- output 2: logpx - logdet
#pragma unroll
  for (int r = 0; r < 16; r++)
    if (c32 == r) {
      const int rw = row0 + drow(r, hb);
      out[2 * BD + rw] = logpx[rw] - ld[r];
    }
}

extern "C" void kernel_launch(void* const* d_in, const int* in_sizes, int n_in,
                              void* d_out, int out_size, void* d_ws,
                              size_t ws_size, hipStream_t stream) {
  (void)in_sizes;
  (void)n_in;
  (void)out_size;
  (void)d_ws;
  (void)ws_size;
  const float* x = (const float*)d_in[0];
  const float* u = (const float*)d_in[1];
  const float* logpx = (const float*)d_in[2];
  const float* eps = (const float*)d_in[3];
  const float* W1x = (const float*)d_in[4];
  const float* W1u = (const float*)d_in[5];
  const float* b1 = (const float*)d_in[6];
  const float* W2 = (const float*)d_in[7];
  const float* b2 = (const float*)d_in[8];
  float* out = (float*)d_out;

  prep_weights<<<32, 256, 0, stream>>>(W1x, W1u, W2);
  iresblock_fused<<<512, 512, 0, stream>>>(x, u, logpx, eps, b1, b2, out);
}

// Round 5
// 1056.654 us; speedup vs baseline: 1.4094x; 1.1344x over previous
//
#include <hip/hip_runtime.h>

// iResBlock logdet estimator — fused, 32x32x16 bf16 MFMA, 3-term hi/lo split.
// B=131072 rows, D=64, H=256, 10 power-series VJP iterations.
// 512-thread blocks (8 waves x 32 rows), 512 blocks, 160 KB LDS.
// ALL weights LDS-resident: w2t staged once; w1t streamed per-nt (dbuf,
// global_load_lds w16, pre-swizzled global layout); w2+w1u restaged after
// phase 1. nt-loops manually unrolled via macros (no runtime array indices
// -> no scratch demotion; s state in named u32x8 vectors).

typedef __attribute__((ext_vector_type(4))) float f32x4;
typedef __attribute__((ext_vector_type(16))) float f32x16;
typedef __attribute__((ext_vector_type(8))) short short8;
typedef __attribute__((ext_vector_type(8))) unsigned u32x8;

#define MFMA32(a, b, c) __builtin_amdgcn_mfma_f32_32x32x16_bf16(a, b, c, 0, 0, 0)

// Pre-split, pre-swizzled weight images (16B slot s holds 8 bf16; logical
// slot sl stored at physical p = sl ^ key(sl); lo-half at p^1):
// w1t [8 slices of 16KB]: B for z=[x|u]@W1cat; slot sl=ks*128+c*4+hb*2,
//   key=(sl>>3)&7.  w2t: B for g=h@W2; sl=d*64+nt*8+kk*4+hb*2, key=(sl>>6)&7.
// w2:  B for t=w@W2^T; sl=h*16+ks*4+hb*2, key=(sl>>4)&7.
// w1u: B for wn=ts@W1u^T (pre-scaled 1/65535); same scheme as w2t.
__device__ __align__(16) short g_w1t_pk[65536];
__device__ __align__(16) short g_w2t_pk[32768];
__device__ __align__(16) short g_w2_pk[32768];
__device__ __align__(16) short g_w1u_pk[32768];

__device__ inline unsigned short bf16r(float f) {  // RNE bf16
  unsigned uu = __float_as_uint(f);
  return (unsigned short)((uu + 0x7FFFu + ((uu >> 16) & 1u)) >> 16);
}

__device__ inline void splitf(float f, short& h, short& l) {
  unsigned uu = __float_as_uint(f);
  unsigned r = uu + 0x7FFFu + ((uu >> 16) & 1u);
  h = (short)(r >> 16);
  float fh = __uint_as_float(r & 0xFFFF0000u);
  l = (short)bf16r(f - fh);
}

__device__ inline void split8(f32x4 a, f32x4 b, short8& hi, short8& lo) {
#pragma unroll
  for (int i = 0; i < 4; i++) {
    short hh, ll;
    splitf(a[i], hh, ll);
    hi[i] = hh;
    lo[i] = ll;
  }
#pragma unroll
  for (int i = 0; i < 4; i++) {
    short hh, ll;
    splitf(b[i], hh, ll);
    hi[4 + i] = hh;
    lo[4 + i] = ll;
  }
}

__global__ void prep_weights(const float* __restrict__ W1x,
                             const float* __restrict__ W1u,
                             const float* __restrict__ W2) {
  const int tid = blockIdx.x * blockDim.x + threadIdx.x;
  const int nth = gridDim.x * blockDim.x;
  const float inv = 1.f / 65535.f;
  for (int i = tid; i < 32768; i += nth) {  // w1t: i = h*128 + k
    const int h = i >> 7, k = i & 127;
    const float v = (k < 64) ? W1x[k * 256 + h] : W1u[(k - 64) * 256 + h];
    short hh, ll;
    splitf(v, hh, ll);
    const int sl = (k >> 4) * 128 + (h & 31) * 4 + ((k >> 3) & 1) * 2;
    const int p = sl ^ ((sl >> 3) & 7);
    const int base = (h >> 5) * 8192, j = k & 7;
    g_w1t_pk[base + p * 8 + j] = hh;
    g_w1t_pk[base + (p ^ 1) * 8 + j] = ll;
  }
  for (int i = tid; i < 16384; i += nth) {  // w2t: i = d*256 + h
    const int d = i >> 8, h = i & 255;
    short hh, ll;
    splitf(W2[h * 64 + d], hh, ll);
    const int sl = d * 64 + (h >> 5) * 8 + ((h >> 4) & 1) * 4 + ((h >> 3) & 1) * 2;
    const int p = sl ^ ((sl >> 6) & 7);
    const int j = h & 7;
    g_w2t_pk[p * 8 + j] = hh;
    g_w2t_pk[(p ^ 1) * 8 + j] = ll;
  }
  for (int i = tid; i < 16384; i += nth) {  // w2: i = h*64 + d
    const int h = i >> 6, d = i & 63;
    short hh, ll;
    splitf(W2[i], hh, ll);
    const int sl = h * 16 + (d >> 4) * 4 + ((d >> 3) & 1) * 2;
    const int p = sl ^ ((sl >> 4) & 7);
    const int j = d & 7;
    g_w2_pk[p * 8 + j] = hh;
    g_w2_pk[(p ^ 1) * 8 + j] = ll;
  }
  for (int i = tid; i < 16384; i += nth) {  // w1u: i = d*256 + h
    const int d = i >> 8, h = i & 255;
    short hh, ll;
    splitf(W1u[i] * inv, hh, ll);
    const int sl = d * 64 + (h >> 5) * 8 + ((h >> 4) & 1) * 4 + ((h >> 3) & 1) * 2;
    const int p = sl ^ ((sl >> 6) & 7);
    const int j = h & 7;
    g_w1u_pk[p * 8 + j] = hh;
    g_w1u_pk[(p ^ 1) * 8 + j] = ll;
  }
}

__device__ inline void gl16(const void* g, void* l) {
  __builtin_amdgcn_global_load_lds(
      (const __attribute__((address_space(1))) void*)g,
      (__attribute__((address_space(3))) void*)l, 16, 0, 0);
}

// Exchange-buffer swizzle ([32 rows][32 cols] f32 per wave).
__device__ inline int swz(int row, int col) {
  return row * 32 + (col ^ ((row & 7) << 2));
}
__device__ inline int drow(int r, int hb) {  // 32x32 D-layout row (m74/m101)
  return (r & 3) + 8 * (r >> 2) + 4 * hb;
}

__device__ inline void exch2(float* buf, const f32x16& t, int hb, int c32,
                             short8& ah0, short8& al0, short8& ah1,
                             short8& al1) {
#pragma unroll
  for (int r = 0; r < 16; r++) buf[swz(drow(r, hb), c32)] = t[r];
  f32x4 fa = *(const f32x4*)&buf[swz(c32, hb * 8)];
  f32x4 fb = *(const f32x4*)&buf[swz(c32, hb * 8 + 4)];
  split8(fa, fb, ah0, al0);
  fa = *(const f32x4*)&buf[swz(c32, 16 + hb * 8)];
  fb = *(const f32x4*)&buf[swz(c32, 16 + hb * 8 + 4)];
  split8(fa, fb, ah1, al1);
}

// ---- phase-1 per-h-tile body (manual unroll; all indices compile-time) ----
#define PH1(NT, RB, WB, SPK, DO_STAGE)                                         \
  {                                                                            \
    if (DO_STAGE) {                                                            \
      const char* gsrc = ((const char*)g_w1t_pk) + ((NT) + 1) * 16384;         \
      char* ldst = ((char*)s_wA) + (WB)*16384;                                 \
      gl16(gsrc + tid * 16, ldst + tid * 16);                                  \
      gl16(gsrc + 8192 + tid * 16, ldst + 8192 + tid * 16);                    \
    }                                                                          \
    f32x16 za = z16;                                                           \
    f32x16 zb = z16;                                                           \
    _Pragma("unroll") for (int ks = 0; ks < 4; ks++) {                         \
      const int ix = (((ks * 128 + c32 * 4 + hb * 2) ^ kq) * 8) + (RB)*8192;   \
      const short8 bh = *(const short8*)&s_wA[ix];                             \
      const short8 bl = *(const short8*)&s_wA[ix ^ 8];                         \
      za = MFMA32(a1h[ks], bh, za);                                            \
      za = MFMA32(a1h[ks], bl, za);                                            \
      za = MFMA32(a1l[ks], bh, za);                                            \
    }                                                                          \
    _Pragma("unroll") for (int ks = 4; ks < 8; ks++) {                         \
      const int ix = (((ks * 128 + c32 * 4 + hb * 2) ^ kq) * 8) + (RB)*8192;   \
      const short8 bh = *(const short8*)&s_wA[ix];                             \
      const short8 bl = *(const short8*)&s_wA[ix ^ 8];                         \
      zb = MFMA32(a1h[ks], bh, zb);                                            \
      zb = MFMA32(a1h[ks], bl, zb);                                            \
      zb = MFMA32(a1l[ks], bh, zb);                                            \
    }                                                                          \
    f32x16 zacc = za + zb;                                                     \
    const float bias = b1[(NT)*32 + c32];                                      \
    f32x16 hv;                                                                 \
    _Pragma("unroll") for (int r = 0; r < 16; r++) {                           \
      float zz = zacc[r] + bias;                                               \
      hv[r] = zz > 0.f ? zz : __expf(zz) - 1.f;                                \
    }                                                                          \
    _Pragma("unroll") for (int rp = 0; rp < 8; rp++) {                         \
      float s0 = hv[2 * rp] > 0.f ? 1.f : hv[2 * rp] + 1.f;                    \
      float s1 = hv[2 * rp + 1] > 0.f ? 1.f : hv[2 * rp + 1] + 1.f;            \
      SPK[rp] = ((unsigned)(s1 * 65535.f + 0.5f) << 16) |                      \
                (unsigned)(s0 * 65535.f + 0.5f);                               \
    }                                                                          \
    short8 a2h0, a2l0, a2h1, a2l1;                                             \
    exch2(xbuf, hv, hb, c32, a2h0, a2l0, a2h1, a2l1);                          \
    _Pragma("unroll") for (int dt = 0; dt < 2; dt++) {                         \
      const int i0 = ((dt * 2048 + c32 * 64 + (NT)*8 + 0 + hb * 2) ^ kc) * 8;  \
      const int i1 = ((dt * 2048 + c32 * 64 + (NT)*8 + 4 + hb * 2) ^ kc) * 8;  \
      const short8 bh0 = *(const short8*)&s_wB[i0];                            \
      const short8 bl0 = *(const short8*)&s_wB[i0 ^ 8];                        \
      const short8 bh1 = *(const short8*)&s_wB[i1];                            \
      const short8 bl1 = *(const short8*)&s_wB[i1 ^ 8];                        \
      gacc[dt] = MFMA32(a2h0, bh0, gacc[dt]);                                  \
      gacc[dt] = MFMA32(a2h0, bl0, gacc[dt]);                                  \
      gacc[dt] = MFMA32(a2l0, bh0, gacc[dt]);                                  \
      gacc[dt] = MFMA32(a2h1, bh1, gacc[dt]);                                  \
      gacc[dt] = MFMA32(a2h1, bl1, gacc[dt]);                                  \
      gacc[dt] = MFMA32(a2l1, bh1, gacc[dt]);                                  \
    }                                                                          \
    __syncthreads();                                                           \
  }

// ---- power-series per-h-tile body ----
#define PW(NT, SPK)                                                            \
  {                                                                            \
    f32x16 ta = z16;                                                           \
    f32x16 tb = z16;                                                           \
    __builtin_amdgcn_s_setprio(1);                                             \
    _Pragma("unroll") for (int ks = 0; ks < 2; ks++) {                         \
      const int ix = (((NT)*512 + c32 * 16 + ks * 4 + hb * 2) ^ kc) * 8;       \
      const short8 bh = *(const short8*)&s_wA[ix];                             \
      const short8 bl = *(const short8*)&s_wA[ix ^ 8];                         \
      ta = MFMA32(a3h[ks], bh, ta);                                            \
      ta = MFMA32(a3h[ks], bl, ta);                                            \
      ta = MFMA32(a3l[ks], bh, ta);                                            \
    }                                                                          \
    _Pragma("unroll") for (int ks = 2; ks < 4; ks++) {                         \
      const int ix = (((NT)*512 + c32 * 16 + ks * 4 + hb * 2) ^ kc) * 8;       \
      const short8 bh = *(const short8*)&s_wA[ix];                             \
      const short8 bl = *(const short8*)&s_wA[ix ^ 8];                         \
      tb = MFMA32(a3h[ks], bh, tb);                                            \
      tb = MFMA32(a3h[ks], bl, tb);                                            \
      tb = MFMA32(a3l[ks], bh, tb);                                            \
    }                                                                          \
    __builtin_amdgcn_s_setprio(0);                                             \
    f32x16 tc = ta + tb;                                                       \
    _Pragma("unroll") for (int r = 0; r < 16; r++) {                           \
      const float sv = (float)((SPK[r >> 1] >> ((r & 1) * 16)) & 0xFFFFu);     \
      tc[r] *= sv;                                                             \
    }                                                                          \
    short8 a4h0, a4l0, a4h1, a4l1;                                             \
    exch2(xbuf, tc, hb, c32, a4h0, a4l0, a4h1, a4l1);                          \
    __builtin_amdgcn_s_setprio(1);                                             \
    {                                                                          \
      const int i00 = ((c32 * 64 + (NT)*8 + 0 + hb * 2) ^ kc) * 8;             \
      const int i01 = ((c32 * 64 + (NT)*8 + 4 + hb * 2) ^ kc) * 8;             \
      const int i10 = ((2048 + c32 * 64 + (NT)*8 + 0 + hb * 2) ^ kc) * 8;      \
      const int i11 = ((2048 + c32 * 64 + (NT)*8 + 4 + hb * 2) ^ kc) * 8;      \
      short8 bh = *(const short8*)&s_wB[i00];                                  \
      short8 bl = *(const short8*)&s_wB[i00 ^ 8];                              \
      wn0 = MFMA32(a4h0, bh, wn0);                                             \
      wn0 = MFMA32(a4h0, bl, wn0);                                             \
      wn0 = MFMA32(a4l0, bh, wn0);                                             \
      bh = *(const short8*)&s_wB[i01];                                         \
      bl = *(const short8*)&s_wB[i01 ^ 8];                                     \
      wn0 = MFMA32(a4h1, bh, wn0);                                             \
      wn0 = MFMA32(a4h1, bl, wn0);                                             \
      wn0 = MFMA32(a4l1, bh, wn0);                                             \
      bh = *(const short8*)&s_wB[i10];                                         \
      bl = *(const short8*)&s_wB[i10 ^ 8];                                     \
      wn1 = MFMA32(a4h0, bh, wn1);                                             \
      wn1 = MFMA32(a4h0, bl, wn1);                                             \
      wn1 = MFMA32(a4l0, bh, wn1);                                             \
      bh = *(const short8*)&s_wB[i11];                                         \
      bl = *(const short8*)&s_wB[i11 ^ 8];                                     \
      wn1 = MFMA32(a4h1, bh, wn1);                                             \
      wn1 = MFMA32(a4h1, bl, wn1);                                             \
      wn1 = MFMA32(a4l1, bh, wn1);                                             \
    }                                                                          \
    __builtin_amdgcn_s_setprio(0);                                             \
  }

__global__ __launch_bounds__(512, 2) void iresblock_fused(
    const float* __restrict__ x, const float* __restrict__ u,
    const float* __restrict__ logpx, const float* __restrict__ eps,
    const float* __restrict__ b1, const float* __restrict__ b2,
    float* __restrict__ out) {
  constexpr int BD = 131072 * 64;
  __shared__ __align__(16) short s_wA[32768];      // 64KB: w1t dbuf -> w2
  __shared__ __align__(16) short s_wB[32768];      // 64KB: w2t -> w1u
  __shared__ __align__(16) float s_xch[8][1024];   // 32KB exchange
  const int tid = threadIdx.x;
  const int lane = tid & 63;
  const int wave = tid >> 6;
  const int c32 = lane & 31, hb = lane >> 5;
  const int kq = (c32 >> 1) & 7;  // w1t swizzle key
  const int kc = c32 & 7;         // w2t/w2/w1u swizzle key
  float* xbuf = &s_xch[wave][0];
  const int row0 = (blockIdx.x * 8 + wave) * 32;
  const f32x16 z16 = {0.f, 0.f, 0.f, 0.f, 0.f, 0.f, 0.f, 0.f,
                      0.f, 0.f, 0.f, 0.f, 0.f, 0.f, 0.f, 0.f};

  // ---- stage w2t (64KB) + w1t slice 0 (16KB) via global_load_lds w16
  {
    const char* gw2t = (const char*)g_w2t_pk;
    char* lB = (char*)s_wB;
#pragma unroll
    for (int i = 0; i < 8; i++)
      gl16(gw2t + i * 8192 + tid * 16, lB + i * 8192 + tid * 16);
    const char* gw1 = (const char*)g_w1t_pk;
    char* lA = (char*)s_wA;
    gl16(gw1 + tid * 16, lA + tid * 16);
    gl16(gw1 + 8192 + tid * 16, lA + 8192 + tid * 16);
  }

  // ---- overlap: x pass-through + matmul1 A-fragments from global x|u
  {
    const float* src = x + row0 * 64;
    float* dst = out + row0 * 64;
#pragma unroll
    for (int i = 0; i < 8; i++) {
      f32x4 v = *(const f32x4*)(src + i * 256 + lane * 4);
      __builtin_nontemporal_store(v, (f32x4*)(dst + i * 256 + lane * 4));
    }
  }
  short8 a1h[8], a1l[8];
  {
    const int arow = row0 + c32;
#pragma unroll
    for (int ks = 0; ks < 8; ks++) {
      const float* p = (ks < 4 ? x : u) + arow * 64 + (ks & 3) * 16 + hb * 8;
      split8(*(const f32x4*)p, *(const f32x4*)(p + 4), a1h[ks], a1l[ks]);
    }
  }
  __syncthreads();

  // ---- phase 1: z -> h=elu -> {s pack, g accum}; w1t streamed per nt
  u32x8 spkv0, spkv1, spkv2, spkv3, spkv4, spkv5, spkv6, spkv7;
  f32x16 gacc[2] = {z16, z16};
  PH1(0, 0, 1, spkv0, 1)
  PH1(1, 1, 0, spkv1, 1)
  PH1(2, 0, 1, spkv2, 1)
  PH1(3, 1, 0, spkv3, 1)
  PH1(4, 0, 1, spkv4, 1)
  PH1(5, 1, 0, spkv5, 1)
  PH1(6, 0, 1, spkv6, 1)
  PH1(7, 1, 0, spkv7, 0)

  // ---- restage: w2 -> s_wA, w1u -> s_wB (drained by the next barrier)
  {
    const char* gw2 = (const char*)g_w2_pk;
    const char* gwu = (const char*)g_w1u_pk;
    char* lA = (char*)s_wA;
    char* lB = (char*)s_wB;
#pragma unroll
    for (int i = 0; i < 8; i++) {
      gl16(gw2 + i * 8192 + tid * 16, lA + i * 8192 + tid * 16);
      gl16(gwu + i * 8192 + tid * 16, lB + i * 8192 + tid * 16);
    }
  }

  // ---- overlap restage latency: v output, eps load, w0 exchange
#pragma unroll
  for (int dt = 0; dt < 2; dt++) {
    const float bias = b2[dt * 32 + c32];
#pragma unroll
    for (int r = 0; r < 16; r++) {
      const int rw = row0 + drow(r, hb);
      const int d = dt * 32 + c32;
      __builtin_nontemporal_store(u[rw * 64 + d] + gacc[dt][r] + bias,
                                  &out[BD + rw * 64 + d]);
    }
  }
  f32x16 e0, e1;
#pragma unroll
  for (int r = 0; r < 16; r++) {
    e0[r] = eps[(row0 + drow(r, hb)) * 64 + c32];
    e1[r] = eps[(row0 + drow(r, hb)) * 64 + 32 + c32];
  }
  short8 a3h[4], a3l[4];
  exch2(xbuf, e0, hb, c32, a3h[0], a3l[0], a3h[1], a3l[1]);
  exch2(xbuf, e1, hb, c32, a3h[2], a3l[2], a3h[3], a3l[3]);
  float ld[16];
#pragma unroll
  for (int r = 0; r < 16; r++) ld[r] = 0.f;
  __syncthreads();

  // ---- power series: wn = ((w @ W2^T) * s) @ W1u^T, 10 iterations
#pragma unroll 1
  for (int k = 1; k <= 10; k++) {
    f32x16 wn0 = z16, wn1 = z16;
    PW(0, spkv0)
    PW(1, spkv1)
    PW(2, spkv2)
    PW(3, spkv3)
    PW(4, spkv4)
    PW(5, spkv5)
    PW(6, spkv6)
    PW(7, spkv7)
    const float coeff = ((k & 1) ? 1.f : -1.f) / (float)k;
#pragma unroll
    for (int r = 0; r < 16; r++)
      ld[r] += coeff * (wn0[r] * e0[r] + wn1[r] * e1[r]);
    if (k < 10) {
      exch2(xbuf, wn0, hb, c32, a3h[0], a3l[0], a3h[1], a3l[1]);
      exch2(xbuf, wn1, hb, c32, a3h[2], a3l[2], a3h[3], a3l[3]);
    }
  }

  // ---- reduce over the 32 lanes sharing each row
#pragma unroll
  for (int r = 0; r < 16; r++)
#pragma unroll
    for (int m = 1; m < 32; m <<= 1) ld[r] += __shfl_xor(ld[r], m, 64);

  // ---- output 2: logpx - logdet
#pragma unroll
  for (int r = 0; r < 16; r++)
    if (c32 == r) {
      const int rw = row0 + drow(r, hb);
      out[2 * BD + rw] = logpx[rw] - ld[r];
    }
}

extern "C" void kernel_launch(void* const* d_in, const int* in_sizes, int n_in,
                              void* d_out, int out_size, void* d_ws,
                              size_t ws_size, hipStream_t stream) {
  (void)in_sizes;
  (void)n_in;
  (void)out_size;
  (void)d_ws;
  (void)ws_size;
  const float* x = (const float*)d_in[0];
  const float* u = (const float*)d_in[1];
  const float* logpx = (const float*)d_in[2];
  const float* eps = (const float*)d_in[3];
  const float* W1x = (const float*)d_in[4];
  const float* W1u = (const float*)d_in[5];
  const float* b1 = (const float*)d_in[6];
  const float* W2 = (const float*)d_in[7];
  const float* b2 = (const float*)d_in[8];
  float* out = (float*)d_out;

  prep_weights<<<32, 256, 0, stream>>>(W1x, W1u, W2);
  iresblock_fused<<<512, 512, 0, stream>>>(x, u, logpx, eps, b1, b2, out);
}

// Round 6
// 452.463 us; speedup vs baseline: 3.2914x; 2.3353x over previous
//
#include <hip/hip_runtime.h>

// iResBlock logdet estimator — fused, 16x16x32 bf16 MFMA, 3-term hi/lo split.
// B=131072 rows, D=64, H=256, 10 power-series VJP iterations.
// 16 rows/wave (state fits registers: no spills), 8 waves/block, 1024 blocks.
// All weights LDS-resident (144KB): w1t streamed in 4 slices (dbuf) + w2t,
// then restaged to w2 + w1u for the power loop. Fragment-contiguous LDS
// layouts (conflict-free floor); logdet via V = sum coeff_k w_k (linearity).

typedef __attribute__((ext_vector_type(4))) float f32x4;
typedef __attribute__((ext_vector_type(8))) short short8;
typedef __attribute__((ext_vector_type(8))) unsigned u32x8;

#define MFMA16(a, b, c) __builtin_amdgcn_mfma_f32_16x16x32_bf16(a, b, c, 0, 0, 0)

// Pre-split weights, fragment-major: unit = 16B of 8 bf16 (hi block, then lo
// block). A wave's (tile,chunk) read = 64 consecutive units (conflict-free).
// w1t: 4 slices of 32KB (hi 16KB | lo 16KB), slice j = h-tiles 4j..4j+3.
// w2t [d][h], w2 [h][d], w1u [d][h] (w1u pre-scaled 1/65535 for u16 s).
__device__ __align__(16) short g_w1t_pk[65536];
__device__ __align__(16) short g_w2t_pk[32768];
__device__ __align__(16) short g_w2_pk[32768];
__device__ __align__(16) short g_w1u_pk[32768];

__device__ inline unsigned short bf16r(float f) {  // RNE bf16
  unsigned uu = __float_as_uint(f);
  return (unsigned short)((uu + 0x7FFFu + ((uu >> 16) & 1u)) >> 16);
}

__device__ inline void splitf(float f, short& h, short& l) {
  unsigned uu = __float_as_uint(f);
  unsigned r = uu + 0x7FFFu + ((uu >> 16) & 1u);
  h = (short)(r >> 16);
  float fh = __uint_as_float(r & 0xFFFF0000u);
  l = (short)bf16r(f - fh);
}

__device__ inline void split8(f32x4 a, f32x4 b, short8& hi, short8& lo) {
#pragma unroll
  for (int i = 0; i < 4; i++) {
    short hh, ll;
    splitf(a[i], hh, ll);
    hi[i] = hh;
    lo[i] = ll;
  }
#pragma unroll
  for (int i = 0; i < 4; i++) {
    short hh, ll;
    splitf(b[i], hh, ll);
    hi[4 + i] = hh;
    lo[4 + i] = ll;
  }
}

__global__ void prep_weights(const float* __restrict__ W1x,
                             const float* __restrict__ W1u,
                             const float* __restrict__ W2) {
  const int tid = blockIdx.x * blockDim.x + threadIdx.x;
  const int nth = gridDim.x * blockDim.x;
  const float inv = 1.f / 65535.f;
  for (int i = tid; i < 32768; i += nth) {  // w1t: i = h*128 + k
    const int h = i >> 7, k = i & 127;
    const float v = (k < 64) ? W1x[k * 256 + h] : W1u[(k - 64) * 256 + h];
    short hh, ll;
    splitf(v, hh, ll);
    const int unit = (((h >> 4) & 3) * 4 + (k >> 5)) * 64 + (h & 15) * 4 +
                     ((k >> 3) & 3);
    const int a = (h >> 6) * 16384 + unit * 8 + (k & 7);
    g_w1t_pk[a] = hh;
    g_w1t_pk[a + 8192] = ll;
  }
  for (int i = tid; i < 16384; i += nth) {  // w2t: i = d*256 + h
    const int d = i >> 8, h = i & 255;
    short hh, ll;
    splitf(W2[h * 64 + d], hh, ll);
    const int unit =
        ((d >> 4) * 8 + (h >> 5)) * 64 + (d & 15) * 4 + ((h >> 3) & 3);
    const int a = unit * 8 + (h & 7);
    g_w2t_pk[a] = hh;
    g_w2t_pk[a + 16384] = ll;
  }
  for (int i = tid; i < 16384; i += nth) {  // w2: i = h*64 + d
    const int h = i >> 6, d = i & 63;
    short hh, ll;
    splitf(W2[i], hh, ll);
    const int unit =
        ((h >> 4) * 2 + (d >> 5)) * 64 + (h & 15) * 4 + ((d >> 3) & 3);
    const int a = unit * 8 + (d & 7);
    g_w2_pk[a] = hh;
    g_w2_pk[a + 16384] = ll;
  }
  for (int i = tid; i < 16384; i += nth) {  // w1u: i = d*256 + h
    const int d = i >> 8, h = i & 255;
    short hh, ll;
    splitf(W1u[i] * inv, hh, ll);
    const int unit =
        ((d >> 4) * 8 + (h >> 5)) * 64 + (d & 15) * 4 + ((h >> 3) & 3);
    const int a = unit * 8 + (h & 7);
    g_w1u_pk[a] = hh;
    g_w1u_pk[a + 16384] = ll;
  }
}

__device__ inline void gl16(const void* g, void* l) {
  __builtin_amdgcn_global_load_lds(
      (const __attribute__((address_space(1))) void*)g,
      (__attribute__((address_space(3))) void*)l, 16, 0, 0);
}

// Exchange buffer [16 rows][32 cols] f32, XOR swizzle: writes 2/bank (free),
// b128 reads at the 8-words/bank floor.
__device__ inline int swz16(int row, int col) {
  return row * 32 + (col ^ ((row & 7) << 2));
}

// ---- phase-1 tile: z -> hv = elu(z); pack s into two u32 words ----
#define PH1TILE(NT, RB, HV, W0REF, W1REF)                                      \
  {                                                                            \
    f32x4 za = z4, zb = z4;                                                    \
    _Pragma("unroll") for (int ks = 0; ks < 2; ks++) {                         \
      const int hb_ = (RB)*16384 + (((NT)&3) * 4 + ks) * 512 + cg;             \
      const short8 bh = *(const short8*)&s_wA[hb_];                            \
      const short8 bl = *(const short8*)&s_wA[hb_ + 8192];                     \
      za = MFMA16(a1h[ks], bh, za);                                            \
      za = MFMA16(a1h[ks], bl, za);                                            \
      za = MFMA16(a1l[ks], bh, za);                                            \
    }                                                                          \
    _Pragma("unroll") for (int ks = 2; ks < 4; ks++) {                         \
      const int hb_ = (RB)*16384 + (((NT)&3) * 4 + ks) * 512 + cg;             \
      const short8 bh = *(const short8*)&s_wA[hb_];                            \
      const short8 bl = *(const short8*)&s_wA[hb_ + 8192];                     \
      zb = MFMA16(a1h[ks], bh, zb);                                            \
      zb = MFMA16(a1h[ks], bl, zb);                                            \
      zb = MFMA16(a1l[ks], bh, zb);                                            \
    }                                                                          \
    const f32x4 zc = za + zb;                                                  \
    const float bi_ = b1[(NT)*16 + c];                                         \
    _Pragma("unroll") for (int r = 0; r < 4; r++) {                            \
      const float zz = zc[r] + bi_;                                            \
      HV[r] = zz > 0.f ? zz : __expf(zz) - 1.f;                                \
    }                                                                          \
    {                                                                          \
      float s0 = HV[0] > 0.f ? 1.f : HV[0] + 1.f;                              \
      float s1 = HV[1] > 0.f ? 1.f : HV[1] + 1.f;                              \
      W0REF = ((unsigned)(s1 * 65535.f + 0.5f) << 16) |                        \
              (unsigned)(s0 * 65535.f + 0.5f);                                 \
      s0 = HV[2] > 0.f ? 1.f : HV[2] + 1.f;                                    \
      s1 = HV[3] > 0.f ? 1.f : HV[3] + 1.f;                                    \
      W1REF = ((unsigned)(s1 * 65535.f + 0.5f) << 16) |                        \
              (unsigned)(s0 * 65535.f + 0.5f);                                 \
    }                                                                          \
  }

// ---- phase-1 pair: exchange 32 h-cols, one K=32 chunk of g = h@W2 ----
#define PH1PAIR(P, HVA, HVB)                                                   \
  {                                                                            \
    _Pragma("unroll") for (int r = 0; r < 4; r++) {                            \
      xbuf[swz16(g4 + r, c)] = HVA[r];                                         \
      xbuf[swz16(g4 + r, 16 + c)] = HVB[r];                                    \
    }                                                                          \
    const f32x4 fa = *(const f32x4*)&xbuf[swz16(c, g8)];                       \
    const f32x4 fb = *(const f32x4*)&xbuf[swz16(c, g8 + 4)];                   \
    short8 a2h_, a2l_;                                                         \
    split8(fa, fb, a2h_, a2l_);                                                \
    __builtin_amdgcn_s_setprio(1);                                             \
    _Pragma("unroll") for (int dt = 0; dt < 4; dt++) {                         \
      const int hb_ = (dt * 8 + (P)) * 512 + cg;                               \
      const short8 bh = *(const short8*)&s_wB[hb_];                            \
      const short8 bl = *(const short8*)&s_wB[hb_ + 16384];                    \
      gacc[dt] = MFMA16(a2h_, bh, gacc[dt]);                                   \
      gacc[dt] = MFMA16(a2h_, bl, gacc[dt]);                                   \
      gacc[dt] = MFMA16(a2l_, bh, gacc[dt]);                                   \
    }                                                                          \
    __builtin_amdgcn_s_setprio(0);                                             \
  }

#define PH1J(J, SPKV)                                                          \
  {                                                                            \
    if ((J) < 3) {                                                             \
      const char* gs_ = ((const char*)g_w1t_pk) + ((J) + 1) * 32768;           \
      char* ld_ = ((char*)s_wA) + (((J) + 1) & 1) * 32768;                     \
      _Pragma("unroll") for (int i = 0; i < 4; i++)                            \
          gl16(gs_ + i * 8192 + tid * 16, ld_ + i * 8192 + tid * 16);          \
    }                                                                          \
    f32x4 hvA, hvB;                                                            \
    PH1TILE(4 * (J) + 0, (J)&1, hvA, SPKV[0], SPKV[1])                         \
    PH1TILE(4 * (J) + 1, (J)&1, hvB, SPKV[2], SPKV[3])                         \
    PH1PAIR(2 * (J), hvA, hvB)                                                 \
    PH1TILE(4 * (J) + 2, (J)&1, hvA, SPKV[4], SPKV[5])                         \
    PH1TILE(4 * (J) + 3, (J)&1, hvB, SPKV[6], SPKV[7])                         \
    PH1PAIR(2 * (J) + 1, hvA, hvB)                                             \
    __syncthreads();                                                           \
  }

// ---- power tile: t = w @ W2^T (one 16-col tile), then t *= s ----
#define PWT(NT, TV, SW0, SW1)                                                  \
  {                                                                            \
    f32x4 ta = z4, tb = z4;                                                    \
    __builtin_amdgcn_s_setprio(1);                                             \
    {                                                                          \
      const int hb_ = ((NT)*2 + 0) * 512 + cg;                                 \
      const short8 bh = *(const short8*)&s_wA[hb_];                            \
      const short8 bl = *(const short8*)&s_wA[hb_ + 16384];                    \
      ta = MFMA16(a3h0, bh, ta);                                               \
      ta = MFMA16(a3h0, bl, ta);                                               \
      ta = MFMA16(a3l0, bh, ta);                                               \
    }                                                                          \
    {                                                                          \
      const int hb_ = ((NT)*2 + 1) * 512 + cg;                                 \
      const short8 bh = *(const short8*)&s_wA[hb_];                            \
      const short8 bl = *(const short8*)&s_wA[hb_ + 16384];                    \
      tb = MFMA16(a3h1, bh, tb);                                               \
      tb = MFMA16(a3h1, bl, tb);                                               \
      tb = MFMA16(a3l1, bh, tb);                                               \
    }                                                                          \
    __builtin_amdgcn_s_setprio(0);                                             \
    TV = ta + tb;                                                              \
    TV[0] *= (float)((SW0)&0xFFFFu);                                           \
    TV[1] *= (float)((SW0) >> 16);                                             \
    TV[2] *= (float)((SW1)&0xFFFFu);                                           \
    TV[3] *= (float)((SW1) >> 16);                                             \
  }

// ---- power pair: exchange ts chunk, accumulate wn += ts_chunk @ W1u^T ----
#define PWPAIR(P, TVA, TVB)                                                    \
  {                                                                            \
    _Pragma("unroll") for (int r = 0; r < 4; r++) {                            \
      xbuf[swz16(g4 + r, c)] = TVA[r];                                         \
      xbuf[swz16(g4 + r, 16 + c)] = TVB[r];                                    \
    }                                                                          \
    const f32x4 fa = *(const f32x4*)&xbuf[swz16(c, g8)];                       \
    const f32x4 fb = *(const f32x4*)&xbuf[swz16(c, g8 + 4)];                   \
    short8 a4h_, a4l_;                                                         \
    split8(fa, fb, a4h_, a4l_);                                                \
    __builtin_amdgcn_s_setprio(1);                                             \
    _Pragma("unroll") for (int dt = 0; dt < 4; dt++) {                         \
      const int hb_ = (dt * 8 + (P)) * 512 + cg;                               \
      const short8 bh = *(const short8*)&s_wB[hb_];                            \
      const short8 bl = *(const short8*)&s_wB[hb_ + 16384];                    \
      wn[dt] = MFMA16(a4h_, bh, wn[dt]);                                       \
      wn[dt] = MFMA16(a4h_, bl, wn[dt]);                                       \
      wn[dt] = MFMA16(a4l_, bh, wn[dt]);                                       \
    }                                                                          \
    __builtin_amdgcn_s_setprio(0);                                             \
  }

// ---- exchange a 2-tile f32 pair into one K=32 A-fragment (hi/lo) ----
#define EXCHW(WA, WB, AH, AL)                                                  \
  {                                                                            \
    _Pragma("unroll") for (int r = 0; r < 4; r++) {                            \
      xbuf[swz16(g4 + r, c)] = WA[r];                                          \
      xbuf[swz16(g4 + r, 16 + c)] = WB[r];                                     \
    }                                                                          \
    const f32x4 fa = *(const f32x4*)&xbuf[swz16(c, g8)];                       \
    const f32x4 fb = *(const f32x4*)&xbuf[swz16(c, g8 + 4)];                   \
    split8(fa, fb, AH, AL);                                                    \
  }

__global__ __launch_bounds__(512, 2) void iresblock_fused(
    const float* __restrict__ x, const float* __restrict__ u,
    const float* __restrict__ logpx, const float* __restrict__ eps,
    const float* __restrict__ b1, const float* __restrict__ b2,
    float* __restrict__ out) {
  constexpr int BD = 131072 * 64;
  __shared__ __align__(16) short s_wA[32768];     // w1t dbuf -> w2
  __shared__ __align__(16) short s_wB[32768];     // w2t -> w1u
  __shared__ __align__(16) float s_xch[8][512];   // 2KB exchange per wave
  const int tid = threadIdx.x;
  const int lane = tid & 63;
  const int wave = tid >> 6;
  const int c = lane & 15, g = lane >> 4;
  const int g4 = g * 4, g8 = g * 8;
  const int cg = c * 32 + g * 8;  // fragment-slot offset (shorts)
  float* xbuf = &s_xch[wave][0];
  const int row0 = (blockIdx.x * 8 + wave) * 16;
  const f32x4 z4 = {0.f, 0.f, 0.f, 0.f};

  // ---- stage w1t slice 0 + w2t
  {
    const char* gA = (const char*)g_w1t_pk;
    char* lA = (char*)s_wA;
#pragma unroll
    for (int i = 0; i < 4; i++)
      gl16(gA + i * 8192 + tid * 16, lA + i * 8192 + tid * 16);
    const char* gB = (const char*)g_w2t_pk;
    char* lB = (char*)s_wB;
#pragma unroll
    for (int i = 0; i < 8; i++)
      gl16(gB + i * 8192 + tid * 16, lB + i * 8192 + tid * 16);
  }

  // ---- overlap: x pass-through + matmul1 A-frags from x|u
  {
    const float* src = x + row0 * 64;
    float* dst = out + row0 * 64;
#pragma unroll
    for (int i = 0; i < 4; i++) {
      const f32x4 v = *(const f32x4*)(src + i * 256 + lane * 4);
      __builtin_nontemporal_store(v, (f32x4*)(dst + i * 256 + lane * 4));
    }
  }
  short8 a1h[4], a1l[4];
  {
    const int arow = row0 + c;
#pragma unroll
    for (int ks = 0; ks < 4; ks++) {
      const float* p = (ks < 2 ? x : u) + arow * 64 + (ks & 1) * 32 + g8;
      split8(*(const f32x4*)p, *(const f32x4*)(p + 4), a1h[ks], a1l[ks]);
    }
  }
  __syncthreads();

  // ---- phase 1
  u32x8 spk0, spk1, spk2, spk3;
  f32x4 gacc[4] = {z4, z4, z4, z4};
  PH1J(0, spk0)
  PH1J(1, spk1)
  PH1J(2, spk2)
  PH1J(3, spk3)

  // ---- restage: w2 -> s_wA, w1u -> s_wB
  {
    const char* g2 = (const char*)g_w2_pk;
    const char* gu = (const char*)g_w1u_pk;
    char* lA = (char*)s_wA;
    char* lB = (char*)s_wB;
#pragma unroll
    for (int i = 0; i < 8; i++) {
      gl16(g2 + i * 8192 + tid * 16, lA + i * 8192 + tid * 16);
      gl16(gu + i * 8192 + tid * 16, lB + i * 8192 + tid * 16);
    }
  }

  // ---- overlap restage: v = u + g + b2, eps -> w0 A-frags
#pragma unroll
  for (int dt = 0; dt < 4; dt++) {
    const float bi_ = b2[dt * 16 + c];
#pragma unroll
    for (int r = 0; r < 4; r++) {
      const int rw = row0 + g4 + r;
      const int d = dt * 16 + c;
      __builtin_nontemporal_store(u[rw * 64 + d] + gacc[dt][r] + bi_,
                                  &out[BD + rw * 64 + d]);
    }
  }
  short8 a3h0, a3l0, a3h1, a3l1;
  {
    f32x4 e0, e1, e2, e3;
#pragma unroll
    for (int r = 0; r < 4; r++) {
      const float* er = eps + (row0 + g4 + r) * 64;
      e0[r] = er[c];
      e1[r] = er[16 + c];
      e2[r] = er[32 + c];
      e3[r] = er[48 + c];
    }
    EXCHW(e0, e1, a3h0, a3l0)
    EXCHW(e2, e3, a3h1, a3l1)
  }
  f32x4 V[4] = {z4, z4, z4, z4};
  __syncthreads();

  // ---- power series: wn = ((w @ W2^T) * s) @ W1u^T; V += coeff_k * wn
#pragma unroll 1
  for (int k = 1; k <= 10; k++) {
    f32x4 wn[4] = {z4, z4, z4, z4};
    f32x4 t0, t1;
    PWT(0, t0, spk0[0], spk0[1])
    PWT(1, t1, spk0[2], spk0[3])
    PWPAIR(0, t0, t1)
    PWT(2, t0, spk0[4], spk0[5])
    PWT(3, t1, spk0[6], spk0[7])
    PWPAIR(1, t0, t1)
    PWT(4, t0, spk1[0], spk1[1])
    PWT(5, t1, spk1[2], spk1[3])
    PWPAIR(2, t0, t1)
    PWT(6, t0, spk1[4], spk1[5])
    PWT(7, t1, spk1[6], spk1[7])
    PWPAIR(3, t0, t1)
    PWT(8, t0, spk2[0], spk2[1])
    PWT(9, t1, spk2[2], spk2[3])
    PWPAIR(4, t0, t1)
    PWT(10, t0, spk2[4], spk2[5])
    PWT(11, t1, spk2[6], spk2[7])
    PWPAIR(5, t0, t1)
    PWT(12, t0, spk3[0], spk3[1])
    PWT(13, t1, spk3[2], spk3[3])
    PWPAIR(6, t0, t1)
    PWT(14, t0, spk3[4], spk3[5])
    PWT(15, t1, spk3[6], spk3[7])
    PWPAIR(7, t0, t1)
    const float coeff = ((k & 1) ? 1.f : -1.f) / (float)k;
#pragma unroll
    for (int dt = 0; dt < 4; dt++) V[dt] += coeff * wn[dt];
    if (k < 10) {
      EXCHW(wn[0], wn[1], a3h0, a3l0)
      EXCHW(wn[2], wn[3], a3h1, a3l1)
    }
  }

  // ---- logdet = V . eps (reload eps), reduce over 16 c-lanes
  float p[4] = {0.f, 0.f, 0.f, 0.f};
#pragma unroll
  for (int r = 0; r < 4; r++) {
    const float* er = eps + (row0 + g4 + r) * 64;
    p[r] = V[0][r] * er[c] + V[1][r] * er[16 + c] + V[2][r] * er[32 + c] +
           V[3][r] * er[48 + c];
  }
#pragma unroll
  for (int r = 0; r < 4; r++) {
    p[r] += __shfl_xor(p[r], 1, 64);
    p[r] += __shfl_xor(p[r], 2, 64);
    p[r] += __shfl_xor(p[r], 4, 64);
    p[r] += __shfl_xor(p[r], 8, 64);
  }
  if (c < 4) {
    const int rw = row0 + g4 + c;
    const float ld0 = c == 0 ? p[0] : c == 1 ? p[1] : c == 2 ? p[2] : p[3];
    out[2 * BD + rw] = logpx[rw] - ld0;
  }
}

extern "C" void kernel_launch(void* const* d_in, const int* in_sizes, int n_in,
                              void* d_out, int out_size, void* d_ws,
                              size_t ws_size, hipStream_t stream) {
  (void)in_sizes;
  (void)n_in;
  (void)out_size;
  (void)d_ws;
  (void)ws_size;
  const float* x = (const float*)d_in[0];
  const float* u = (const float*)d_in[1];
  const float* logpx = (const float*)d_in[2];
  const float* eps = (const float*)d_in[3];
  const float* W1x = (const float*)d_in[4];
  const float* W1u = (const float*)d_in[5];
  const float* b1 = (const float*)d_in[6];
  const float* W2 = (const float*)d_in[7];
  const float* b2 = (const float*)d_in[8];
  float* out = (float*)d_out;

  prep_weights<<<64, 256, 0, stream>>>(W1x, W1u, W2);
  iresblock_fused<<<1024, 512, 0, stream>>>(x, u, logpx, eps, b1, b2, out);
}

// Round 7
// 398.746 us; speedup vs baseline: 3.7348x; 1.1347x over previous
//
#include <hip/hip_runtime.h>

// iResBlock logdet estimator — fused, 16x16x32 bf16 MFMA, 3-term hi/lo split.
// B=131072 rows, D=64, H=256, 10 power-series VJP iterations.
// TRANSPOSED FLOW: weights = A operand (LDS, prep-packed in fragment layout
// with the consumer k-slot permutation tau baked in); activations = B operand.
// Every MFMA output (feature-major D-layout) feeds the next matmul's B-frag
// directly from the lane's own registers — no LDS exchange, no shuffles.
// Splits via v_cvt_pk_bf16_f32. Power loop is barrier-free.

typedef __attribute__((ext_vector_type(4))) float f32x4;
typedef __attribute__((ext_vector_type(8))) short short8;

#define MFMA16(a, b, c) __builtin_amdgcn_mfma_f32_16x16x32_bf16(a, b, c, 0, 0, 0)

// Pre-split weights, fragment-major. Block = (tile,chunk) = 1024 shorts:
// [hi 512 | lo 512]; unit (16B) index within block = c*4+g (c = A-row =
// output feature within tile, g = k-group). k-slot (g,i):
//   w1t (A=W1cat^T [h][kin], k=kin): tau identity, kin = ks*32+g*8+i.
//   w2t (A=W2^T [d][h], k=h), w2 (A=W2 [h][d], k=d), w1u (A=W1u [d][h], k=h):
//   tau paired: slot (g, i) = tile (2j + (i>=4)), feature 4g + (i&3) —
//   matching the producer D-layout (lane (g,c) holds feats 4g+r of each tile).
// w1u pre-scaled by 1/65535 (u16 fixed-point s fold).
__device__ __align__(16) short g_w1t_pk[65536];  // 16 tiles x 4 chunks
__device__ __align__(16) short g_w2t_pk[32768];  // 4 d-tiles x 8 chunks
__device__ __align__(16) short g_w2_pk[32768];   // 16 h-tiles x 2 chunks
__device__ __align__(16) short g_w1u_pk[32768];  // 4 d-tiles x 8 chunks

__device__ inline unsigned short bf16r(float f) {  // RNE bf16
  unsigned uu = __float_as_uint(f);
  return (unsigned short)((uu + 0x7FFFu + ((uu >> 16) & 1u)) >> 16);
}
__device__ inline void splitf(float f, short& h, short& l) {
  unsigned uu = __float_as_uint(f);
  unsigned r = uu + 0x7FFFu + ((uu >> 16) & 1u);
  h = (short)(r >> 16);
  float fh = __uint_as_float(r & 0xFFFF0000u);
  l = (short)bf16r(f - fh);
}

__global__ void prep_weights(const float* __restrict__ W1x,
                             const float* __restrict__ W1u,
                             const float* __restrict__ W2) {
  const int tid = blockIdx.x * blockDim.x + threadIdx.x;
  const int nth = gridDim.x * blockDim.x;
  const float inv = 1.f / 65535.f;
  for (int idx = tid; idx < 32768; idx += nth) {  // w1t: idx = h*128 + kin
    const int h = idx >> 7, k = idx & 127;
    const float v = (k < 64) ? W1x[k * 256 + h] : W1u[(k - 64) * 256 + h];
    short hh, ll;
    splitf(v, hh, ll);
    const int a = (h >> 6) * 16384 + (((h >> 4) & 3) * 4 + (k >> 5)) * 1024 +
                  ((h & 15) * 4 + ((k >> 3) & 3)) * 8 + (k & 7);
    g_w1t_pk[a] = hh;
    g_w1t_pk[a + 512] = ll;
  }
  for (int idx = tid; idx < 16384; idx += nth) {  // w2t: idx = d*256 + h
    const int d = idx >> 8, h = idx & 255;
    short hh, ll;
    splitf(W2[h * 64 + d], hh, ll);
    const int a = ((d >> 4) * 8 + (h >> 5)) * 1024 +
                  ((d & 15) * 4 + ((h & 15) >> 2)) * 8 +
                  (((h >> 4) & 1) * 4 + (h & 3));
    g_w2t_pk[a] = hh;
    g_w2t_pk[a + 512] = ll;
  }
  for (int idx = tid; idx < 16384; idx += nth) {  // w2: idx = h*64 + d
    const int h = idx >> 6, d = idx & 63;
    short hh, ll;
    splitf(W2[idx], hh, ll);
    const int a = ((h >> 4) * 2 + (d >> 5)) * 1024 +
                  ((h & 15) * 4 + ((d & 15) >> 2)) * 8 +
                  (((d >> 4) & 1) * 4 + (d & 3));
    g_w2_pk[a] = hh;
    g_w2_pk[a + 512] = ll;
  }
  for (int idx = tid; idx < 16384; idx += nth) {  // w1u: idx = d*256 + h
    const int d = idx >> 8, h = idx & 255;
    short hh, ll;
    splitf(W1u[idx] * inv, hh, ll);
    const int a = ((d >> 4) * 8 + (h >> 5)) * 1024 +
                  ((d & 15) * 4 + ((h & 15) >> 2)) * 8 +
                  (((h >> 4) & 1) * 4 + (h & 3));
    g_w1u_pk[a] = hh;
    g_w1u_pk[a + 512] = ll;
  }
}

__device__ inline void gl16(const void* g, void* l) {
  __builtin_amdgcn_global_load_lds(
      (const __attribute__((address_space(1))) void*)g,
      (__attribute__((address_space(3))) void*)l, 16, 0, 0);
}

__device__ inline unsigned cvtpk(float a, float b) {  // lo16=bf16(a), hi16=bf16(b)
  unsigned r;
  asm("v_cvt_pk_bf16_f32 %0, %1, %2" : "=v"(r) : "v"(a), "v"(b));
  return r;
}

// Build a K=32 B-frag (hi/lo bf16 pair) from two D-layout f32x4 tiles:
// slots 0..3 = ta regs, 4..7 = tb regs (the tau mapping baked into weights).
__device__ inline void mkfrag(const f32x4 ta, const f32x4 tb, short8& hi,
                              short8& lo) {
  union {
    unsigned w[4];
    short8 v;
  } H, L;
#pragma unroll
  for (int p = 0; p < 2; p++) {
    const unsigned hA = cvtpk(ta[2 * p], ta[2 * p + 1]);
    H.w[p] = hA;
    const float fA0 = __uint_as_float(hA << 16);
    const float fA1 = __uint_as_float(hA & 0xFFFF0000u);
    L.w[p] = cvtpk(ta[2 * p] - fA0, ta[2 * p + 1] - fA1);
    const unsigned hB = cvtpk(tb[2 * p], tb[2 * p + 1]);
    H.w[2 + p] = hB;
    const float fB0 = __uint_as_float(hB << 16);
    const float fB1 = __uint_as_float(hB & 0xFFFF0000u);
    L.w[2 + p] = cvtpk(tb[2 * p] - fB0, tb[2 * p + 1] - fB1);
  }
  hi = H.v;
  lo = L.v;
}

__global__ __launch_bounds__(512, 2) void iresblock_fused(
    const float* __restrict__ x, const float* __restrict__ u,
    const float* __restrict__ logpx, const float* __restrict__ eps,
    const float* __restrict__ b1, const float* __restrict__ b2,
    float* __restrict__ out) {
  constexpr int BD = 131072 * 64;
  __shared__ __align__(16) short s_wA[32768];  // w1t dbuf (2x16384) -> w2
  __shared__ __align__(16) short s_wB[32768];  // w2t -> w1u
  const int tid = threadIdx.x;
  const int lane = tid & 63;
  const int wave = tid >> 6;
  const int c = lane & 15, g = lane >> 4;
  const int g4 = g * 4, g8 = g * 8;
  const int cg2 = (c * 4 + g) * 8;  // fragment unit offset (shorts)
  const int row0 = (blockIdx.x * 8 + wave) * 16;
  const f32x4 z4 = {0.f, 0.f, 0.f, 0.f};

  // ---- stage w1t slice 0 (32KB) + w2t (64KB)
  {
    const char* gA = (const char*)g_w1t_pk;
    char* lA = (char*)s_wA;
#pragma unroll
    for (int i = 0; i < 4; i++)
      gl16(gA + i * 8192 + tid * 16, lA + i * 8192 + tid * 16);
    const char* gB = (const char*)g_w2t_pk;
    char* lB = (char*)s_wB;
#pragma unroll
    for (int i = 0; i < 8; i++)
      gl16(gB + i * 8192 + tid * 16, lB + i * 8192 + tid * 16);
  }

  // ---- overlap: x pass-through + input B-frags (identity tau, from global)
  {
    const float* src = x + row0 * 64;
    float* dst = out + row0 * 64;
#pragma unroll
    for (int i = 0; i < 4; i++) {
      const f32x4 v = *(const f32x4*)(src + i * 256 + lane * 4);
      __builtin_nontemporal_store(v, (f32x4*)(dst + i * 256 + lane * 4));
    }
  }
  short8 b1h[4], b1l[4];  // B[col=c][kin = ks*32 + g8 + i]
  {
    const int arow = row0 + c;
#pragma unroll
    for (int ks = 0; ks < 4; ks++) {
      const float* p = (ks < 2 ? x : u) + arow * 64 + (ks & 1) * 32 + g8;
      const f32x4 va = *(const f32x4*)p;
      const f32x4 vb = *(const f32x4*)(p + 4);
      short hh, ll;
      union {
        unsigned w[4];
        short8 v;
      } H, L;
#pragma unroll
      for (int pp = 0; pp < 2; pp++) {
        const unsigned hA = cvtpk(va[2 * pp], va[2 * pp + 1]);
        H.w[pp] = hA;
        L.w[pp] = cvtpk(va[2 * pp] - __uint_as_float(hA << 16),
                        va[2 * pp + 1] - __uint_as_float(hA & 0xFFFF0000u));
        const unsigned hB = cvtpk(vb[2 * pp], vb[2 * pp + 1]);
        H.w[2 + pp] = hB;
        L.w[2 + pp] = cvtpk(vb[2 * pp] - __uint_as_float(hB << 16),
                            vb[2 * pp + 1] - __uint_as_float(hB & 0xFFFF0000u));
      }
      b1h[ks] = H.v;
      b1l[ks] = L.v;
      (void)hh;
      (void)ll;
    }
  }
  __syncthreads();

  // ---- phase 1: z^T = W1cat^T(A) @ input(B); h = elu; s pack; g^T accum
  unsigned spk[16][2];  // s = elu'(z) u16 fixed pairs, [h-tile][r>>1]
  f32x4 gacc[4] = {z4, z4, z4, z4};
  f32x4 hvp = z4;
#pragma unroll
  for (int J = 0; J < 4; J++) {
    if (J < 3) {  // stage next slice into the other half
      const char* gs = ((const char*)g_w1t_pk) + (J + 1) * 32768;
      char* ld = ((char*)s_wA) + (((J + 1) & 1) ? 32768 : 0);
#pragma unroll
      for (int i = 0; i < 4; i++)
        gl16(gs + i * 8192 + tid * 16, ld + i * 8192 + tid * 16);
    }
#pragma unroll
    for (int t = 0; t < 4; t++) {
      const int nt = 4 * J + t;
      f32x4 za = z4, zb = z4;
      __builtin_amdgcn_s_setprio(1);
#pragma unroll
      for (int ks = 0; ks < 2; ks++) {
        const int ix = (J & 1) * 16384 + (t * 4 + ks) * 1024 + cg2;
        const short8 ah = *(const short8*)&s_wA[ix];
        const short8 al = *(const short8*)&s_wA[ix + 512];
        za = MFMA16(ah, b1h[ks], za);
        za = MFMA16(al, b1h[ks], za);
        za = MFMA16(ah, b1l[ks], za);
      }
#pragma unroll
      for (int ks = 2; ks < 4; ks++) {
        const int ix = (J & 1) * 16384 + (t * 4 + ks) * 1024 + cg2;
        const short8 ah = *(const short8*)&s_wA[ix];
        const short8 al = *(const short8*)&s_wA[ix + 512];
        zb = MFMA16(ah, b1h[ks], zb);
        zb = MFMA16(al, b1h[ks], zb);
        zb = MFMA16(ah, b1l[ks], zb);
      }
      __builtin_amdgcn_s_setprio(0);
      const f32x4 zc = za + zb;
      const f32x4 b1v = *(const f32x4*)(b1 + nt * 16 + g4);
      f32x4 hv;
#pragma unroll
      for (int r = 0; r < 4; r++) {
        const float zz = zc[r] + b1v[r];
        hv[r] = zz > 0.f ? zz : __expf(zz) - 1.f;
      }
      {
        const float s0 = hv[0] > 0.f ? 1.f : hv[0] + 1.f;
        const float s1 = hv[1] > 0.f ? 1.f : hv[1] + 1.f;
        const float s2 = hv[2] > 0.f ? 1.f : hv[2] + 1.f;
        const float s3 = hv[3] > 0.f ? 1.f : hv[3] + 1.f;
        spk[nt][0] = ((unsigned)(s1 * 65535.f + 0.5f) << 16) |
                     (unsigned)(s0 * 65535.f + 0.5f);
        spk[nt][1] = ((unsigned)(s3 * 65535.f + 0.5f) << 16) |
                     (unsigned)(s2 * 65535.f + 0.5f);
      }
      if (t & 1) {  // pair (nt-1, nt) complete -> k-chunk nt>>1 of matmul2
        short8 bh_, bl_;
        mkfrag(hvp, hv, bh_, bl_);
        const int j2 = nt >> 1;
        __builtin_amdgcn_s_setprio(1);
#pragma unroll
        for (int dt = 0; dt < 4; dt++) {
          const int ix = (dt * 8 + j2) * 1024 + cg2;
          const short8 ah = *(const short8*)&s_wB[ix];
          const short8 al = *(const short8*)&s_wB[ix + 512];
          gacc[dt] = MFMA16(ah, bh_, gacc[dt]);
          gacc[dt] = MFMA16(al, bh_, gacc[dt]);
          gacc[dt] = MFMA16(ah, bl_, gacc[dt]);
        }
        __builtin_amdgcn_s_setprio(0);
      } else {
        hvp = hv;
      }
    }
    __syncthreads();
  }

  // ---- restage: w2 -> s_wA, w1u -> s_wB
  {
    const char* g2 = (const char*)g_w2_pk;
    const char* gu = (const char*)g_w1u_pk;
    char* lA = (char*)s_wA;
    char* lB = (char*)s_wB;
#pragma unroll
    for (int i = 0; i < 8; i++) {
      gl16(g2 + i * 8192 + tid * 16, lA + i * 8192 + tid * 16);
      gl16(gu + i * 8192 + tid * 16, lB + i * 8192 + tid * 16);
    }
  }

  // ---- overlap restage: v = u + g + b2 (feature-major D-layout stores)
#pragma unroll
  for (int dt = 0; dt < 4; dt++) {
    const f32x4 b2v = *(const f32x4*)(b2 + dt * 16 + g4);
    const f32x4 uv = *(const f32x4*)(u + (row0 + c) * 64 + dt * 16 + g4);
    f32x4 vv;
#pragma unroll
    for (int r = 0; r < 4; r++) vv[r] = uv[r] + gacc[dt][r] + b2v[r];
    __builtin_nontemporal_store(vv,
                                (f32x4*)(out + BD + (row0 + c) * 64 + dt * 16 + g4));
  }
  // w0 = eps -> B-frags (tau-paired loads straight from global)
  short8 wbh[2], wbl[2];
#pragma unroll
  for (int ch = 0; ch < 2; ch++) {
    const f32x4 ea = *(const f32x4*)(eps + (row0 + c) * 64 + ch * 32 + g4);
    const f32x4 eb = *(const f32x4*)(eps + (row0 + c) * 64 + ch * 32 + 16 + g4);
    mkfrag(ea, eb, wbh[ch], wbl[ch]);
  }
  f32x4 V[4] = {z4, z4, z4, z4};
  __syncthreads();

  // ---- power series (barrier-free): wn = ((w @ W2^T) * s) @ W1u^T
#pragma unroll 1
  for (int k = 1; k <= 10; k++) {
    f32x4 wn[4] = {z4, z4, z4, z4};
#pragma unroll
    for (int j = 0; j < 8; j++) {
      f32x4 tA = z4, tB = z4;
      __builtin_amdgcn_s_setprio(1);
#pragma unroll
      for (int ch = 0; ch < 2; ch++) {
        const int ix = (4 * j + ch) * 1024 + cg2;  // tile 2j
        const short8 ah = *(const short8*)&s_wA[ix];
        const short8 al = *(const short8*)&s_wA[ix + 512];
        tA = MFMA16(ah, wbh[ch], tA);
        tA = MFMA16(al, wbh[ch], tA);
        tA = MFMA16(ah, wbl[ch], tA);
      }
#pragma unroll
      for (int ch = 0; ch < 2; ch++) {
        const int ix = (4 * j + 2 + ch) * 1024 + cg2;  // tile 2j+1
        const short8 ah = *(const short8*)&s_wA[ix];
        const short8 al = *(const short8*)&s_wA[ix + 512];
        tB = MFMA16(ah, wbh[ch], tB);
        tB = MFMA16(al, wbh[ch], tB);
        tB = MFMA16(ah, wbl[ch], tB);
      }
      __builtin_amdgcn_s_setprio(0);
      // ts = t * s (u16 fixed; 1/65535 folded into w1u)
      tA[0] *= (float)(spk[2 * j][0] & 0xFFFFu);
      tA[1] *= (float)(spk[2 * j][0] >> 16);
      tA[2] *= (float)(spk[2 * j][1] & 0xFFFFu);
      tA[3] *= (float)(spk[2 * j][1] >> 16);
      tB[0] *= (float)(spk[2 * j + 1][0] & 0xFFFFu);
      tB[1] *= (float)(spk[2 * j + 1][0] >> 16);
      tB[2] *= (float)(spk[2 * j + 1][1] & 0xFFFFu);
      tB[3] *= (float)(spk[2 * j + 1][1] >> 16);
      short8 th, tl;
      mkfrag(tA, tB, th, tl);
      __builtin_amdgcn_s_setprio(1);
#pragma unroll
      for (int dt = 0; dt < 4; dt++) {
        const int ix = (dt * 8 + j) * 1024 + cg2;
        const short8 ah = *(const short8*)&s_wB[ix];
        const short8 al = *(const short8*)&s_wB[ix + 512];
        wn[dt] = MFMA16(ah, th, wn[dt]);
        wn[dt] = MFMA16(al, th, wn[dt]);
        wn[dt] = MFMA16(ah, tl, wn[dt]);
      }
      __builtin_amdgcn_s_setprio(0);
    }
    const float coeff = ((k & 1) ? 1.f : -1.f) / (float)k;
#pragma unroll
    for (int dt = 0; dt < 4; dt++) V[dt] += coeff * wn[dt];
    if (k < 10) {  // next iteration's B-frags straight from wn registers
      mkfrag(wn[0], wn[1], wbh[0], wbl[0]);
      mkfrag(wn[2], wn[3], wbh[1], wbl[1]);
    }
  }

  // ---- logdet = (sum_k coeff_k w_k) . eps ; reduce over the 4 g-lanes
  float acc = 0.f;
#pragma unroll
  for (int dt = 0; dt < 4; dt++) {
    const f32x4 ev = *(const f32x4*)(eps + (row0 + c) * 64 + dt * 16 + g4);
    acc += V[dt][0] * ev[0] + V[dt][1] * ev[1] + V[dt][2] * ev[2] +
           V[dt][3] * ev[3];
  }
  acc += __shfl_xor(acc, 16, 64);
  acc += __shfl_xor(acc, 32, 64);
  if (g == 0) {
    out[2 * BD + row0 + c] = logpx[row0 + c] - acc;
  }
}

extern "C" void kernel_launch(void* const* d_in, const int* in_sizes, int n_in,
                              void* d_out, int out_size, void* d_ws,
                              size_t ws_size, hipStream_t stream) {
  (void)in_sizes;
  (void)n_in;
  (void)out_size;
  (void)d_ws;
  (void)ws_size;
  const float* x = (const float*)d_in[0];
  const float* u = (const float*)d_in[1];
  const float* logpx = (const float*)d_in[2];
  const float* eps = (const float*)d_in[3];
  const float* W1x = (const float*)d_in[4];
  const float* W1u = (const float*)d_in[5];
  const float* b1 = (const float*)d_in[6];
  const float* W2 = (const float*)d_in[7];
  const float* b2 = (const float*)d_in[8];
  float* out = (float*)d_out;

  prep_weights<<<64, 256, 0, stream>>>(W1x, W1u, W2);
  iresblock_fused<<<1024, 512, 0, stream>>>(x, u, logpx, eps, b1, b2, out);
}